// Round 16
// baseline (24.919 us; speedup 1.0000x reference)
//
#include <hip/hip_runtime.h>

// Problem constants (from reference setup_inputs)
#define B_ 64
#define H_ 376
#define W_ 1248
#define N_ 48                // boxes per batch
#define R_ 8                 // rows per chunk (divides 376 = 47*8)
#define GRID_V (H_ / R_)     // 47 row-chunks
#define CPB 4                // chunks (batches) per block
#define GRID_B (B_ / CPB)    // 16
#define NB (GRID_V * GRID_B) // 752 blocks
#define NWORDS (W_ / 32)     // 39 mask words per row
#define MWORDS (R_ * NWORDS) // 312 words per chunk
#define F4ROW (W_ / 4)       // 312 float4 per row
#define BLOCK_MAIN 320       // 5 waves
#define BLOCK_RED 256        // reduce kernel: 4 waves, single block

typedef float f32x4 __attribute__((ext_vector_type(4)));

// Soft barrier: orders LDS ops only (zero -> raster -> consume). Avoids the
// s_waitcnt vmcnt(0) drain hipcc emits before __syncthreads-lowered
// s_barrier, so ISSUE(x0)'s in-flight HBM loads are NOT force-completed
// before the raster (which doesn't read them). CONSUME's x0 register
// dependency is protected by compiler-inserted vmcnt waits as usual.
#define SOFT_BAR()                                                \
    do {                                                          \
        asm volatile("s_waitcnt lgkmcnt(0)" ::: "memory");        \
        __builtin_amdgcn_s_barrier();                             \
    } while (0)

// R16 = R15-exact + soft barriers in the hot path (ONE variable).
// Same mechanism class as the two banked wins: remove serial latency from
// the per-generation critical path (R15: cold box load, -1.66us). R12's
// soft-bar null was confounded by the regressive x1-hoist.
//
// Session ledger:
//   R15 (R9 + isolated box hoist):  PASS 24.72  <- base/best
//   R9  (two-dispatch, nt, CPB=4):  PASS 26.38
//   R10 plain loads 27.19 | R11/R12 x1-hoist 27.34/27.44 | R14 CPB=2 26.91
//   R13 cooperative FAIL | R0-R8 single-kernel ticket family retired
__global__ __launch_bounds__(BLOCK_MAIN) void balancer_partials(
    const float* __restrict__ loss,
    const float* __restrict__ boxes,     // [B, N, 4] = (u1, v1, u2, v2)
    double* __restrict__ ws_fg,          // [NB] unique slots
    double* __restrict__ ws_tot)         // [NB] unique slots
{
    const int vc = blockIdx.x;          // row-chunk
    const int bb = blockIdx.y;          // batch slot: handles bb + 16*c
    const int t  = threadIdx.x;
    const int v0 = vc * R_;

    __shared__ unsigned int mask_flat[CPB * MWORDS];   // 4*312 words = 5 KB
    __shared__ double sred[2 * (BLOCK_MAIN / 64)];

    const bool active = (t < F4ROW);
    const int w  = t >> 3;
    const int sh = (t & 7) * 4;
    double dfg = 0.0, dtot = 0.0;
    f32x4 x0[R_], x1[R_];

#define ISSUE(X, c)                                                              \
    if (active) {                                                                \
        const float* bp = loss + ((size_t)((bb + GRID_B * (c)) * H_ + v0)) * W_  \
                        + (size_t)t * 4;                                         \
        _Pragma("unroll")                                                        \
        for (int r = 0; r < R_; ++r)                                             \
            X[r] = __builtin_nontemporal_load(                                   \
                reinterpret_cast<const f32x4*>(bp + (size_t)r * W_));            \
    }

#define CONSUME(X, c)                                                            \
    if (active) {                                                                \
        float fg = 0.f, tt = 0.f;                                                \
        _Pragma("unroll")                                                        \
        for (int r = 0; r < R_; ++r) {                                           \
            const unsigned int bits =                                            \
                (mask_flat[(c) * MWORDS + r * NWORDS + w] >> sh) & 0xFu;         \
            const f32x4 xv = X[r];                                               \
            tt += (xv.x + xv.y) + (xv.z + xv.w);                                 \
            fg += ((bits & 1u) ? xv.x : 0.f) + ((bits & 2u) ? xv.y : 0.f)        \
                + ((bits & 4u) ? xv.z : 0.f) + ((bits & 8u) ? xv.w : 0.f);       \
        }                                                                        \
        dfg += (double)fg; dtot += (double)tt;                                   \
    }

    // --- Prologue (R15-proven): box float4 first, then chunk-0 loads.
    const bool raster = (t < CPB * N_);
    float4 bx;
    int rc = 0;
    if (raster) {
        rc = t / N_;
        const int i = t - rc * N_;
        const int b = bb + GRID_B * rc;
        bx = *reinterpret_cast<const float4*>(
            boxes + ((size_t)b * N_ + (size_t)i) * 4);
    }
    ISSUE(x0, 0);

    // Zero the mask words (1248 words, threads 0..311 write 4 each).
    if (t < MWORDS) {
        #pragma unroll
        for (int k = 0; k < CPB; ++k) mask_flat[t + k * MWORDS] = 0u;
    }
    SOFT_BAR();                     // zero visible; x0 loads stay in flight

    // Inverted raster: one thread per (chunk, box); box already in registers.
    if (raster) {
        int iu1 = (int)floorf(bx.x);
        int iv1 = (int)floorf(bx.y);
        int iu2 = (int)ceilf(bx.z);
        int iv2 = (int)ceilf(bx.w);
        int r1 = iv1 - v0; r1 = r1 < 0 ? 0 : r1;
        int r2 = iv2 - v0; r2 = r2 > R_ ? R_ : r2;
        iu1 = iu1 < 0 ? 0 : iu1;
        iu2 = iu2 > W_ ? W_ : iu2;
        if (r2 > r1 && iu2 > iu1) {
            const int w1 = iu1 >> 5;
            const int w2 = (iu2 + 31) >> 5;   // exclusive
            for (int ww = w1; ww < w2; ++ww) {
                const int lo = iu1 - (ww << 5);
                const int hi = iu2 - (ww << 5);
                const int l = lo < 0 ? 0 : lo;
                const int h = hi > 32 ? 32 : hi;
                const unsigned int mh = (h == 32) ? 0xFFFFFFFFu : ((1u << h) - 1u);
                const unsigned int m  = mh & ~((1u << l) - 1u);
                for (int r = r1; r < r2; ++r)
                    atomicOr(&mask_flat[rc * MWORDS + r * NWORDS + ww], m);
            }
        }
    }
    SOFT_BAR();                     // raster atomics visible (lgkmcnt-drained)

    // Barrier-free 4-chunk stream with register double-buffering (R9-proven).
    ISSUE(x1, 1); CONSUME(x0, 0);
    ISSUE(x0, 2); CONSUME(x1, 1);
    ISSUE(x1, 3); CONSUME(x0, 2);
    CONSUME(x1, 3);

    // Block reduction in fp64 (5 waves of 64). Cold path: plain barrier.
    #pragma unroll
    for (int off = 32; off > 0; off >>= 1) {
        dfg  += __shfl_down(dfg,  off, 64);
        dtot += __shfl_down(dtot, off, 64);
    }
    const int wave = t >> 6;
    const int lane = t & 63;
    if (lane == 0) { sred[wave] = dfg; sred[(BLOCK_MAIN / 64) + wave] = dtot; }
    __syncthreads();
    if (t == 0) {
        double f = 0.0, s = 0.0;
        #pragma unroll
        for (int i = 0; i < BLOCK_MAIN / 64; ++i) {
            f += sred[i]; s += sred[(BLOCK_MAIN / 64) + i];
        }
        const int bid = bb * GRID_V + vc;
        // Plain unique-slot stores; visibility to the next dispatch is
        // guaranteed by the stream-order kernel boundary.
        ws_fg[bid]  = f;
        ws_tot[bid] = s;
    }
#undef ISSUE
#undef CONSUME
}

// Kernel 2: single block reduces the 752 slot-pairs and writes the 3 outputs.
__global__ __launch_bounds__(BLOCK_RED) void balancer_reduce(
    const double* __restrict__ ws_fg,
    const double* __restrict__ ws_tot,
    float* __restrict__ out)
{
    const int t = threadIdx.x;
    __shared__ double sred[2 * (BLOCK_RED / 64)];

    double fgA = 0.0, totA = 0.0;
    for (int i = t; i < NB; i += BLOCK_RED) {
        fgA  += ws_fg[i];
        totA += ws_tot[i];
    }
    #pragma unroll
    for (int off = 32; off > 0; off >>= 1) {
        fgA  += __shfl_down(fgA,  off, 64);
        totA += __shfl_down(totA, off, 64);
    }
    const int wave = t >> 6;
    const int lane = t & 63;
    if (lane == 0) { sred[wave] = fgA; sred[(BLOCK_RED / 64) + wave] = totA; }
    __syncthreads();
    if (t == 0) {
        double f = 0.0, s = 0.0;
        #pragma unroll
        for (int i = 0; i < BLOCK_RED / 64; ++i) {
            f += sred[i]; s += sred[(BLOCK_RED / 64) + i];
        }
        const double num = (double)B_ * (double)H_ * (double)W_;
        const double fg_loss = 13.0 * f / num;
        const double bg_loss = (s - f) / num;
        out[0] = (float)(fg_loss + bg_loss);
        out[1] = (float)fg_loss;
        out[2] = (float)bg_loss;
    }
}

extern "C" void kernel_launch(void* const* d_in, const int* in_sizes, int n_in,
                              void* d_out, int out_size, void* d_ws, size_t ws_size,
                              hipStream_t stream) {
    const float* loss  = (const float*)d_in[0];   // [B, H, W] fp32
    const float* boxes = (const float*)d_in[1];   // [B, N, 4] fp32
    float* out = (float*)d_out;                   // 3 fp32

    double* ws_fg  = (double*)d_ws;                        // NB doubles
    double* ws_tot = ws_fg + NB;                           // NB doubles

    // Two stream-ordered dispatches; no memset (all slots rewritten each call).
    dim3 grid(GRID_V, GRID_B, 1);
    balancer_partials<<<grid, BLOCK_MAIN, 0, stream>>>(loss, boxes, ws_fg, ws_tot);
    balancer_reduce<<<dim3(1, 1, 1), BLOCK_RED, 0, stream>>>(ws_fg, ws_tot, out);
}

// Round 17
// 24.683 us; speedup vs baseline: 1.0096x; 1.0096x over previous
//
#include <hip/hip_runtime.h>

// Problem constants (from reference setup_inputs)
#define B_ 64
#define H_ 376
#define W_ 1248
#define N_ 48                // boxes per batch
#define R_ 8                 // rows per chunk (divides 376 = 47*8)
#define GRID_V (H_ / R_)     // 47 row-chunks
#define CPB 4                // chunks (batches) per block
#define GRID_B (B_ / CPB)    // 16
#define NB (GRID_V * GRID_B) // 752 blocks
#define NWORDS (W_ / 32)     // 39 mask words per row
#define MWORDS (R_ * NWORDS) // 312 words per chunk
#define F4ROW (W_ / 4)       // 312 float4 per row
#define BLOCK_MAIN 320       // 5 waves
#define BLOCK_RED 256        // reduce kernel: 4 waves, single block

typedef float f32x4 __attribute__((ext_vector_type(4)));

// FINAL (R17) = R15-exact, the session's proven best (24.72us, -13% vs the
// 28.4us session baseline).
//
// Structure: two stream-ordered dispatches (the only harness-proven
// cross-block ordering; single-kernel ticket designs carry a latent
// winner-visibility race, R0-R8). Kernel 1: 752 blocks, each rasterizes
// 4 chunk-masks into LDS and streams 4x8 rows of loss with nt float4
// loads (nt > plain by 0.8us, R10) behind a register-double-buffered
// ladder; box float4 hoisted to the prologue so its cold-miss latency
// hides under the mask-zero+barrier (-1.66us, R15). Kernel 2: one block
// reduces the 752 fp64 slot-pairs.
//
// Measured-closed levers: x1-prefetch (+1.0, R11/R12), soft barriers
// (+0.2, R16), 2x occupancy (+0.5, R14), cooperative sync (FAIL, R13),
// plain loads (+0.8, R10). Budget: ~19.1us pure-stream floor + ~2us
// stream inefficiency (~90% of 6.29TB/s copy ceiling) + ~3.5us
// launch-latency-bound two-dispatch fixed cost.
__global__ __launch_bounds__(BLOCK_MAIN) void balancer_partials(
    const float* __restrict__ loss,
    const float* __restrict__ boxes,     // [B, N, 4] = (u1, v1, u2, v2)
    double* __restrict__ ws_fg,          // [NB] unique slots
    double* __restrict__ ws_tot)         // [NB] unique slots
{
    const int vc = blockIdx.x;          // row-chunk
    const int bb = blockIdx.y;          // batch slot: handles bb + 16*c
    const int t  = threadIdx.x;
    const int v0 = vc * R_;

    __shared__ unsigned int mask_flat[CPB * MWORDS];   // 4*312 words = 5 KB
    __shared__ double sred[2 * (BLOCK_MAIN / 64)];

    const bool active = (t < F4ROW);
    const int w  = t >> 3;
    const int sh = (t & 7) * 4;
    double dfg = 0.0, dtot = 0.0;
    f32x4 x0[R_], x1[R_];

#define ISSUE(X, c)                                                              \
    if (active) {                                                                \
        const float* bp = loss + ((size_t)((bb + GRID_B * (c)) * H_ + v0)) * W_  \
                        + (size_t)t * 4;                                         \
        _Pragma("unroll")                                                        \
        for (int r = 0; r < R_; ++r)                                             \
            X[r] = __builtin_nontemporal_load(                                   \
                reinterpret_cast<const f32x4*>(bp + (size_t)r * W_));            \
    }

#define CONSUME(X, c)                                                            \
    if (active) {                                                                \
        float fg = 0.f, tt = 0.f;                                                \
        _Pragma("unroll")                                                        \
        for (int r = 0; r < R_; ++r) {                                           \
            const unsigned int bits =                                            \
                (mask_flat[(c) * MWORDS + r * NWORDS + w] >> sh) & 0xFu;         \
            const f32x4 xv = X[r];                                               \
            tt += (xv.x + xv.y) + (xv.z + xv.w);                                 \
            fg += ((bits & 1u) ? xv.x : 0.f) + ((bits & 2u) ? xv.y : 0.f)        \
                + ((bits & 4u) ? xv.z : 0.f) + ((bits & 8u) ? xv.w : 0.f);       \
        }                                                                        \
        dfg += (double)fg; dtot += (double)tt;                                   \
    }

    // --- Prologue (R15-proven): box float4 first (its ~200-900cy latency
    // hides under the zero+barrier), then chunk-0 loads. NO x1 hoist.
    const bool raster = (t < CPB * N_);
    float4 bx;
    int rc = 0;
    if (raster) {
        rc = t / N_;
        const int i = t - rc * N_;
        const int b = bb + GRID_B * rc;
        bx = *reinterpret_cast<const float4*>(
            boxes + ((size_t)b * N_ + (size_t)i) * 4);
    }
    ISSUE(x0, 0);

    // Zero the mask words (1248 words, threads 0..311 write 4 each).
    if (t < MWORDS) {
        #pragma unroll
        for (int k = 0; k < CPB; ++k) mask_flat[t + k * MWORDS] = 0u;
    }
    __syncthreads();

    // Inverted raster: one thread per (chunk, box); box already in registers.
    if (raster) {
        int iu1 = (int)floorf(bx.x);
        int iv1 = (int)floorf(bx.y);
        int iu2 = (int)ceilf(bx.z);
        int iv2 = (int)ceilf(bx.w);
        int r1 = iv1 - v0; r1 = r1 < 0 ? 0 : r1;
        int r2 = iv2 - v0; r2 = r2 > R_ ? R_ : r2;
        iu1 = iu1 < 0 ? 0 : iu1;
        iu2 = iu2 > W_ ? W_ : iu2;
        if (r2 > r1 && iu2 > iu1) {
            const int w1 = iu1 >> 5;
            const int w2 = (iu2 + 31) >> 5;   // exclusive
            for (int ww = w1; ww < w2; ++ww) {
                const int lo = iu1 - (ww << 5);
                const int hi = iu2 - (ww << 5);
                const int l = lo < 0 ? 0 : lo;
                const int h = hi > 32 ? 32 : hi;
                const unsigned int mh = (h == 32) ? 0xFFFFFFFFu : ((1u << h) - 1u);
                const unsigned int m  = mh & ~((1u << l) - 1u);
                for (int r = r1; r < r2; ++r)
                    atomicOr(&mask_flat[rc * MWORDS + r * NWORDS + ww], m);
            }
        }
    }
    __syncthreads();

    // Barrier-free 4-chunk stream with register double-buffering (R9-proven).
    ISSUE(x1, 1); CONSUME(x0, 0);
    ISSUE(x0, 2); CONSUME(x1, 1);
    ISSUE(x1, 3); CONSUME(x0, 2);
    CONSUME(x1, 3);

    // Block reduction in fp64 (5 waves of 64).
    #pragma unroll
    for (int off = 32; off > 0; off >>= 1) {
        dfg  += __shfl_down(dfg,  off, 64);
        dtot += __shfl_down(dtot, off, 64);
    }
    const int wave = t >> 6;
    const int lane = t & 63;
    if (lane == 0) { sred[wave] = dfg; sred[(BLOCK_MAIN / 64) + wave] = dtot; }
    __syncthreads();
    if (t == 0) {
        double f = 0.0, s = 0.0;
        #pragma unroll
        for (int i = 0; i < BLOCK_MAIN / 64; ++i) {
            f += sred[i]; s += sred[(BLOCK_MAIN / 64) + i];
        }
        const int bid = bb * GRID_V + vc;
        // Plain unique-slot stores; visibility to the next dispatch is
        // guaranteed by the stream-order kernel boundary.
        ws_fg[bid]  = f;
        ws_tot[bid] = s;
    }
#undef ISSUE
#undef CONSUME
}

// Kernel 2: single block reduces the 752 slot-pairs and writes the 3 outputs.
__global__ __launch_bounds__(BLOCK_RED) void balancer_reduce(
    const double* __restrict__ ws_fg,
    const double* __restrict__ ws_tot,
    float* __restrict__ out)
{
    const int t = threadIdx.x;
    __shared__ double sred[2 * (BLOCK_RED / 64)];

    double fgA = 0.0, totA = 0.0;
    for (int i = t; i < NB; i += BLOCK_RED) {
        fgA  += ws_fg[i];
        totA += ws_tot[i];
    }
    #pragma unroll
    for (int off = 32; off > 0; off >>= 1) {
        fgA  += __shfl_down(fgA,  off, 64);
        totA += __shfl_down(totA, off, 64);
    }
    const int wave = t >> 6;
    const int lane = t & 63;
    if (lane == 0) { sred[wave] = fgA; sred[(BLOCK_RED / 64) + wave] = totA; }
    __syncthreads();
    if (t == 0) {
        double f = 0.0, s = 0.0;
        #pragma unroll
        for (int i = 0; i < BLOCK_RED / 64; ++i) {
            f += sred[i]; s += sred[(BLOCK_RED / 64) + i];
        }
        const double num = (double)B_ * (double)H_ * (double)W_;
        const double fg_loss = 13.0 * f / num;
        const double bg_loss = (s - f) / num;
        out[0] = (float)(fg_loss + bg_loss);
        out[1] = (float)fg_loss;
        out[2] = (float)bg_loss;
    }
}

extern "C" void kernel_launch(void* const* d_in, const int* in_sizes, int n_in,
                              void* d_out, int out_size, void* d_ws, size_t ws_size,
                              hipStream_t stream) {
    const float* loss  = (const float*)d_in[0];   // [B, H, W] fp32
    const float* boxes = (const float*)d_in[1];   // [B, N, 4] fp32
    float* out = (float*)d_out;                   // 3 fp32

    double* ws_fg  = (double*)d_ws;                        // NB doubles
    double* ws_tot = ws_fg + NB;                           // NB doubles

    // Two stream-ordered dispatches; no memset (all slots rewritten each call).
    dim3 grid(GRID_V, GRID_B, 1);
    balancer_partials<<<grid, BLOCK_MAIN, 0, stream>>>(loss, boxes, ws_fg, ws_tot);
    balancer_reduce<<<dim3(1, 1, 1), BLOCK_RED, 0, stream>>>(ws_fg, ws_tot, out);
}